// Round 5
// baseline (1506.721 us; speedup 1.0000x reference)
//
#include <hip/hip_runtime.h>

#define T_TOKENS 4096
#define DM 1024
#define DF 4096
#define KSEL 256
#define DH 64
#define DH2 32

typedef __attribute__((ext_vector_type(8))) short short8;
typedef __attribute__((ext_vector_type(4))) float f32x4;

// exact-libm gelu: ONLY for the router path (scores must stay bitwise stable)
__device__ __forceinline__ float gelu_f(float x) {
    return 0.5f * x * (1.0f + erff(x * 0.70710678118654752440f));
}

// branch-free erf, Abramowitz-Stegun 7.1.26, |err| <= 1.5e-7 abs
__device__ __forceinline__ float erf_fast(float x) {
    float ax = __builtin_fabsf(x);
    float t = __builtin_amdgcn_rcpf(fmaf(0.3275911f, ax, 1.0f));
    float p = 1.061405429f;
    p = fmaf(p, t, -1.453152027f);
    p = fmaf(p, t, 1.421413741f);
    p = fmaf(p, t, -0.284496736f);
    p = fmaf(p, t, 0.254829592f);
    float e = __builtin_amdgcn_exp2f(-ax * ax * 1.44269504088896f);
    float r = fmaf(-p * t, e, 1.0f);
    return __builtin_copysignf(r, x);
}
__device__ __forceinline__ float gelu_fast(float x) {
    return 0.5f * x * (1.0f + erf_fast(x * 0.70710678118654752440f));
}

__device__ __forceinline__ unsigned short bf16_rne(float f) {
    unsigned u = __float_as_uint(f);
    unsigned r = (u + 0x7FFFu + ((u >> 16) & 1u)) >> 16;
    return (unsigned short)r;
}
__device__ __forceinline__ float bf16_to_f(unsigned short h) {
    return __uint_as_float(((unsigned)h) << 16);
}

// ---------------- LayerNorm over last dim (1024), one block per row ----------------
__global__ __launch_bounds__(256) void ln_kernel(const float* __restrict__ x,
                                                 const float* __restrict__ w,
                                                 const float* __restrict__ b,
                                                 float* __restrict__ out) {
    int row = blockIdx.x;
    int tid = threadIdx.x;
    const float4 v = ((const float4*)(x + (size_t)row * DM))[tid];
    float s = v.x + v.y + v.z + v.w;
    float s2 = v.x * v.x + v.y * v.y + v.z * v.z + v.w * v.w;
#pragma unroll
    for (int off = 32; off > 0; off >>= 1) {
        s += __shfl_xor(s, off);
        s2 += __shfl_xor(s2, off);
    }
    __shared__ float ss[4], ss2[4];
    int wave = tid >> 6;
    if ((tid & 63) == 0) { ss[wave] = s; ss2[wave] = s2; }
    __syncthreads();
    s = ss[0] + ss[1] + ss[2] + ss[3];
    s2 = ss2[0] + ss2[1] + ss2[2] + ss2[3];
    float mu = s * (1.0f / DM);
    float var = s2 * (1.0f / DM) - mu * mu;
    float rs = rsqrtf(var + 1e-5f);
    const float4 wv = ((const float4*)w)[tid];
    const float4 bv = ((const float4*)b)[tid];
    float4 o;
    o.x = (v.x - mu) * rs * wv.x + bv.x;
    o.y = (v.y - mu) * rs * wv.y + bv.y;
    o.z = (v.z - mu) * rs * wv.z + bv.z;
    o.w = (v.w - mu) * rs * wv.w + bv.w;
    ((float4*)(out + (size_t)row * DM))[tid] = o;
}

// ---------------- fp32 GEMM (router): C = A[M,K]*B[N,K]^T, 128x128, 8x8 micro ------
// Per-element k-accumulation order bitwise stable across rounds -> top-k safe.
__global__ __launch_bounds__(256) void gemm_f32_128(const float* __restrict__ A,
                                                    const float* __restrict__ B,
                                                    float* __restrict__ C,
                                                    int M, int N, int K, int fuse_gelu) {
    __shared__ __align__(16) float As[16][132];
    __shared__ __align__(16) float Bs[16][132];
    int tid = threadIdx.x;
    int bm = blockIdx.y * 128, bn = blockIdx.x * 128;
    int tr = tid >> 4, tc = tid & 15;

    float4 avr[2], bvr[2];
    auto g_load = [&](int k0) {
#pragma unroll
        for (int s = 0; s < 2; s++) {
            int i = tid * 2 + s;
            int r = i >> 2, q = i & 3;
            avr[s] = *(const float4*)(A + (size_t)(bm + r) * K + k0 + q * 4);
            bvr[s] = *(const float4*)(B + (size_t)(bn + r) * K + k0 + q * 4);
        }
    };

    float acc[8][8] = {};
    g_load(0);
    for (int k0 = 0; k0 < K; k0 += 16) {
        __syncthreads();
#pragma unroll
        for (int s = 0; s < 2; s++) {
            int i = tid * 2 + s;
            int r = i >> 2, q = i & 3;
            As[q * 4 + 0][r] = avr[s].x; As[q * 4 + 1][r] = avr[s].y;
            As[q * 4 + 2][r] = avr[s].z; As[q * 4 + 3][r] = avr[s].w;
            Bs[q * 4 + 0][r] = bvr[s].x; Bs[q * 4 + 1][r] = bvr[s].y;
            Bs[q * 4 + 2][r] = bvr[s].z; Bs[q * 4 + 3][r] = bvr[s].w;
        }
        __syncthreads();
        if (k0 + 16 < K) g_load(k0 + 16);
#pragma unroll
        for (int kk = 0; kk < 16; kk++) {
            float4 a0 = *(const float4*)&As[kk][tr * 8];
            float4 a1 = *(const float4*)&As[kk][tr * 8 + 4];
            float4 b0 = *(const float4*)&Bs[kk][tc * 8];
            float4 b1 = *(const float4*)&Bs[kk][tc * 8 + 4];
            float ar[8] = {a0.x, a0.y, a0.z, a0.w, a1.x, a1.y, a1.z, a1.w};
            float br[8] = {b0.x, b0.y, b0.z, b0.w, b1.x, b1.y, b1.z, b1.w};
#pragma unroll
            for (int i = 0; i < 8; i++)
#pragma unroll
                for (int j = 0; j < 8; j++)
                    acc[i][j] = fmaf(ar[i], br[j], acc[i][j]);
        }
    }
#pragma unroll
    for (int i = 0; i < 8; i++) {
        float* cp = C + (size_t)(bm + tr * 8 + i) * N + bn + tc * 8;
        float4 o0, o1;
        if (fuse_gelu) {
            o0 = make_float4(gelu_f(acc[i][0]), gelu_f(acc[i][1]), gelu_f(acc[i][2]), gelu_f(acc[i][3]));
            o1 = make_float4(gelu_f(acc[i][4]), gelu_f(acc[i][5]), gelu_f(acc[i][6]), gelu_f(acc[i][7]));
        } else {
            o0 = make_float4(acc[i][0], acc[i][1], acc[i][2], acc[i][3]);
            o1 = make_float4(acc[i][4], acc[i][5], acc[i][6], acc[i][7]);
        }
        ((float4*)cp)[0] = o0;
        ((float4*)cp)[1] = o1;
    }
}

// ---------------- bf16 MFMA GEMM: C[M,N] (+)= A[M,K]*B[N,K]^T ---------------------
__global__ __launch_bounds__(256) void gemm_bf16(const short* __restrict__ A,
                                                 const short* __restrict__ B,
                                                 float* __restrict__ C,
                                                 int M, int N, int K, int beta) {
    __shared__ __align__(16) short As[128 * 64];
    __shared__ __align__(16) short Bs[128 * 64];
    int tid = threadIdx.x;
    int bm = blockIdx.y * 128, bn = blockIdx.x * 128;
    int lane = tid & 63, wave = tid >> 6;
    int wm = (wave >> 1) * 64, wn = (wave & 1) * 64;
    int quad = lane >> 4, l16 = lane & 15;
    int sr = tid >> 3, scp = tid & 7;

    short8 areg[4], breg[4];
    auto g_load = [&](int k0) {
#pragma unroll
        for (int j = 0; j < 4; j++) {
            int r = j * 32 + sr;
            int cl = scp ^ (r & 7);
            areg[j] = *(const short8*)(A + (size_t)(bm + r) * K + k0 + cl * 8);
            breg[j] = *(const short8*)(B + (size_t)(bn + r) * K + k0 + cl * 8);
        }
    };

    f32x4 acc[4][4] = {};
    g_load(0);
    for (int k0 = 0; k0 < K; k0 += 64) {
        __syncthreads();
#pragma unroll
        for (int j = 0; j < 4; j++) {
            *(short8*)(As + (j * 256 + tid) * 8) = areg[j];
            *(short8*)(Bs + (j * 256 + tid) * 8) = breg[j];
        }
        __syncthreads();
        if (k0 + 64 < K) g_load(k0 + 64);
#pragma unroll
        for (int kk = 0; kk < 2; kk++) {
            short8 af[4], bf[4];
#pragma unroll
            for (int tm = 0; tm < 4; tm++) {
                int m = wm + tm * 16 + l16;
                int cp = (kk * 4 + quad) ^ (m & 7);
                af[tm] = *(const short8*)(As + m * 64 + cp * 8);
            }
#pragma unroll
            for (int tn = 0; tn < 4; tn++) {
                int n = wn + tn * 16 + l16;
                int cp = (kk * 4 + quad) ^ (n & 7);
                bf[tn] = *(const short8*)(Bs + n * 64 + cp * 8);
            }
#pragma unroll
            for (int tm = 0; tm < 4; tm++)
#pragma unroll
                for (int tn = 0; tn < 4; tn++)
                    acc[tm][tn] = __builtin_amdgcn_mfma_f32_16x16x32_bf16(
                        af[tm], bf[tn], acc[tm][tn], 0, 0, 0);
        }
    }
#pragma unroll
    for (int tm = 0; tm < 4; tm++)
#pragma unroll
        for (int tn = 0; tn < 4; tn++) {
            int row0 = bm + wm + tm * 16 + quad * 4;
            int col = bn + wn + tn * 16 + l16;
#pragma unroll
            for (int r = 0; r < 4; r++) {
                float* p = C + (size_t)(row0 + r) * N + col;
                float v = acc[tm][tn][r];
                if (beta) v += *p;
                *p = v;
            }
        }
}

// ---------------- fp32 -> (hi, lo) bf16 planes ------------------------------------
__global__ __launch_bounds__(256) void cvt_split_kernel(const float* __restrict__ x,
                                                        short* __restrict__ hi,
                                                        short* __restrict__ lo, int n4) {
    int i = blockIdx.x * 256 + threadIdx.x;
    if (i >= n4) return;
    float4 v = ((const float4*)x)[i];
    ushort4 h, l;
    h.x = bf16_rne(v.x); l.x = bf16_rne(v.x - bf16_to_f(h.x));
    h.y = bf16_rne(v.y); l.y = bf16_rne(v.y - bf16_to_f(h.y));
    h.z = bf16_rne(v.z); l.z = bf16_rne(v.z - bf16_to_f(h.z));
    h.w = bf16_rne(v.w); l.w = bf16_rne(v.w - bf16_to_f(h.w));
    ((ushort4*)hi)[i] = h;
    ((ushort4*)lo)[i] = l;
}

__global__ __launch_bounds__(256) void cvt_bf16_kernel(const float* __restrict__ x,
                                                       short* __restrict__ y, int n4) {
    int i = blockIdx.x * 256 + threadIdx.x;
    if (i >= n4) return;
    float4 v = ((const float4*)x)[i];
    ushort4 h;
    h.x = bf16_rne(v.x); h.y = bf16_rne(v.y);
    h.z = bf16_rne(v.z); h.w = bf16_rne(v.w);
    ((ushort4*)y)[i] = h;
}

// ---------------- top-k (k=256 of 4096) per row, exact tie-break ------------------
__device__ __forceinline__ unsigned sortable(float f) {
    unsigned u = __float_as_uint(f);
    return (u & 0x80000000u) ? ~u : (u | 0x80000000u);
}

__global__ __launch_bounds__(256) void topk_kernel(const float* __restrict__ scores,
                                                   int* __restrict__ top_idx) {
    int row = blockIdx.x;
    int tid = threadIdx.x;
    __shared__ unsigned s_keys[DF];
    __shared__ int hist[256];
    __shared__ int sufs[256];
    __shared__ int s_misc[4];
    __shared__ int s_wsums[4];

    const float* sr = scores + (size_t)row * DF;
    for (int i = tid; i < DF; i += 256) s_keys[i] = sortable(sr[i]);

    unsigned prefix = 0;
    int krem = KSEL;
    for (int pass = 0; pass < 4; pass++) {
        int shift = 24 - pass * 8;
        unsigned hmask = (pass == 0) ? 0u : (0xFFFFFFFFu << (shift + 8));
        hist[tid] = 0;
        __syncthreads();
        for (int i = tid; i < DF; i += 256) {
            unsigned u = s_keys[i];
            if ((u & hmask) == prefix) atomicAdd(&hist[(u >> shift) & 0xFF], 1);
        }
        __syncthreads();
        sufs[tid] = hist[tid];
        __syncthreads();
#pragma unroll
        for (int off = 1; off < 256; off <<= 1) {
            int add = (tid + off < 256) ? sufs[tid + off] : 0;
            __syncthreads();
            sufs[tid] += add;
            __syncthreads();
        }
        if (sufs[tid] >= krem && (tid == 255 || sufs[tid + 1] < krem)) {
            s_misc[0] = tid;
            s_misc[1] = sufs[tid] - hist[tid];
        }
        __syncthreads();
        prefix |= ((unsigned)s_misc[0]) << shift;
        krem -= s_misc[1];
        __syncthreads();
    }
    unsigned v = prefix;
    if (tid == 0) s_misc[2] = 0;
    __syncthreads();
    int* out = top_idx + (size_t)row * KSEL;
    for (int i = tid; i < DF; i += 256) {
        if (s_keys[i] > v) {
            int p = atomicAdd(&s_misc[2], 1);
            out[p] = i;
        }
    }
    __syncthreads();
    int base = s_misc[2];
    int lane = tid & 63, wave = tid >> 6;
    int taken = 0;
    for (int chunk = 0; chunk < DF / 256; chunk++) {
        int i = chunk * 256 + tid;
        int flag = (s_keys[i] == v) ? 1 : 0;
        unsigned long long mb = __ballot(flag);
        int before = __popcll(mb & ((1ULL << lane) - 1ULL));
        if (lane == 0) s_wsums[wave] = __popcll(mb);
        __syncthreads();
        int woff = 0;
#pragma unroll
        for (int w = 0; w < 4; w++) if (w < wave) woff += s_wsums[w];
        int total = s_wsums[0] + s_wsums[1] + s_wsums[2] + s_wsums[3];
        int excl = woff + before;
        if (flag && (taken + excl) < krem) out[base + taken + excl] = i;
        taken += total;
        __syncthreads();
    }
}

// ---------------- DeepSets manifold: one block per token, one k per thread --------
// __launch_bounds__(256,3): cap 3 waves/EU -> ~170 VGPR budget so h[64]+g[32]
// live in ARCH VGPRs (at (256) default the allocator picked 52 VGPR + AGPRs,
// adding one v_accvgpr_read per h[] use -> ~2x dynamic VALU instructions).
__global__ __launch_bounds__(256, 3) void manifold_kernel(
    const float* __restrict__ z, const int* __restrict__ top_idx,
    const float* __restrict__ phi1_w, const float* __restrict__ phi1_b,
    const float* __restrict__ ln1w, const float* __restrict__ ln1b,
    const float* __restrict__ phi2_w, const float* __restrict__ phi2_b,
    const float* __restrict__ ln2w, const float* __restrict__ ln2b,
    const float* __restrict__ rho1_w, const float* __restrict__ rho1_b,
    const float* __restrict__ rho2_w, const float* __restrict__ rho2_b,
    float* __restrict__ man) {
    __shared__ float s_ctxp[4 * DH];
    __shared__ float s_ctx[DH];

    int tid = threadIdx.x;
    int t = blockIdx.x;
    int lane = tid & 63, wave = tid >> 6;

    int idx = top_idx[(size_t)t * KSEL + tid];
    float a = gelu_fast(z[(size_t)t * DF + idx]);

    float g[DH2];
    float s = 0.f, s2 = 0.f;
#pragma unroll
    for (int i = 0; i < DH2; i++) {
        float e = fmaf(a, phi1_w[i], phi1_b[i]);
        g[i] = e;
        s += e;
        s2 = fmaf(e, e, s2);
    }
    float mu = s * (1.0f / DH2);
    float rs = rsqrtf(s2 * (1.0f / DH2) - mu * mu + 1e-5f);
#pragma unroll
    for (int i = 0; i < DH2; i++)
        g[i] = gelu_fast(fmaf((g[i] - mu) * rs, ln1w[i], ln1b[i]));

    float h[DH];
#pragma unroll
    for (int j = 0; j < DH; j++) {
        float r = phi2_b[j];
        const float4* w4 = (const float4*)(phi2_w + j * DH2);
#pragma unroll
        for (int i4 = 0; i4 < DH2 / 4; i4++) {
            float4 w = w4[i4];
            r = fmaf(g[4 * i4 + 0], w.x, r);
            r = fmaf(g[4 * i4 + 1], w.y, r);
            r = fmaf(g[4 * i4 + 2], w.z, r);
            r = fmaf(g[4 * i4 + 3], w.w, r);
        }
        h[j] = r;
    }

    float tsum = 0.f, tsq = 0.f;
#pragma unroll
    for (int j = 0; j < DH; j++) { tsum += h[j]; tsq = fmaf(h[j], h[j], tsq); }
    float mu2 = tsum * (1.0f / DH);
    float rs2 = rsqrtf(tsq * (1.0f / DH) - mu2 * mu2 + 1e-5f);
#pragma unroll
    for (int j = 0; j < DH; j++) h[j] = fmaf((h[j] - mu2) * rs2, ln2w[j], ln2b[j]);

#pragma unroll
    for (int j = 0; j < DH; j++) {
        float v = h[j];
#pragma unroll
        for (int st = 1; st < 64; st <<= 1) v += __shfl_xor(v, st);
        if (lane == 0) s_ctxp[wave * DH + j] = v;
    }
    __syncthreads();
    if (tid < DH)
        s_ctx[tid] = (s_ctxp[tid] + s_ctxp[DH + tid] + s_ctxp[2 * DH + tid] +
                      s_ctxp[3 * DH + tid]) * (1.0f / KSEL);
    __syncthreads();

#pragma unroll
    for (int j = 0; j < DH; j++) h[j] += s_ctx[j];
    float m = rho2_b[0];
    for (int p = 0; p < 2 * DH; p++) {
        // two partial sums: shorter dependency chain at 3 waves/EU
        float r0 = rho1_b[p], r1 = 0.f;
        const float4* w4 = (const float4*)(rho1_w + p * DH);
#pragma unroll
        for (int q4 = 0; q4 < DH / 4; q4 += 2) {
            float4 wa = w4[q4];
            float4 wb = w4[q4 + 1];
            r0 = fmaf(h[4 * q4 + 0], wa.x, r0);
            r1 = fmaf(h[4 * q4 + 4], wb.x, r1);
            r0 = fmaf(h[4 * q4 + 1], wa.y, r0);
            r1 = fmaf(h[4 * q4 + 5], wb.y, r1);
            r0 = fmaf(h[4 * q4 + 2], wa.z, r0);
            r1 = fmaf(h[4 * q4 + 6], wb.z, r1);
            r0 = fmaf(h[4 * q4 + 3], wa.w, r0);
            r1 = fmaf(h[4 * q4 + 7], wb.w, r1);
        }
        m = fmaf(gelu_fast(r0 + r1), rho2_w[p], m);
    }
    man[(size_t)t * KSEL + tid] = m;
}

// ---------------- scatter man (as bf16) into zeroed bf16 a_man --------------------
__global__ __launch_bounds__(256) void scatter_bf16_kernel(const float* __restrict__ man,
                                                           const int* __restrict__ top_idx,
                                                           short* __restrict__ a_man) {
    int t = blockIdx.x, k = threadIdx.x;
    a_man[(size_t)t * DF + top_idx[(size_t)t * KSEL + k]] =
        (short)bf16_rne(man[(size_t)t * KSEL + k]);
}

extern "C" void kernel_launch(void* const* d_in, const int* in_sizes, int n_in,
                              void* d_out, int out_size, void* d_ws, size_t ws_size,
                              hipStream_t stream) {
    const float* x      = (const float*)d_in[0];
    const float* W1     = (const float*)d_in[1];
    const float* W2     = (const float*)d_in[2];
    const float* Wr1    = (const float*)d_in[3];
    const float* Wr2    = (const float*)d_in[4];
    const float* ln_w   = (const float*)d_in[5];
    const float* ln_b   = (const float*)d_in[6];
    const float* phi1_w = (const float*)d_in[7];
    const float* phi1_b = (const float*)d_in[8];
    const float* pl1w   = (const float*)d_in[9];
    const float* pl1b   = (const float*)d_in[10];
    const float* phi2_w = (const float*)d_in[11];
    const float* phi2_b = (const float*)d_in[12];
    const float* pl2w   = (const float*)d_in[13];
    const float* pl2b   = (const float*)d_in[14];
    const float* rho1_w = (const float*)d_in[15];
    const float* rho1_b = (const float*)d_in[16];
    const float* rho2_w = (const float*)d_in[17];
    const float* rho2_b = (const float*)d_in[18];
    float* out = (float*)d_out;

    char* ws = (char*)d_ws;
    size_t off = 0;
    auto alloc = [&](size_t bytes) {
        char* p = ws + off;
        off += (bytes + 255) & ~(size_t)255;
        return p;
    };
    float* xn     = (float*)alloc(sizeof(float) * (size_t)T_TOKENS * DM);   // 16 MB
    float* h      = (float*)alloc(sizeof(float) * (size_t)T_TOKENS * DM);   // 16 MB
    float* scores = (float*)alloc(sizeof(float) * (size_t)T_TOKENS * DF);   // 64 MB
    float* z      = (float*)alloc(sizeof(float) * (size_t)T_TOKENS * DF);   // 64 MB
    int*   tidx   = (int*)alloc(sizeof(int) * (size_t)T_TOKENS * KSEL);     // 4 MB
    float* man    = (float*)alloc(sizeof(float) * (size_t)T_TOKENS * KSEL); // 4 MB

    // Region reuse (stream-serial, lifetimes disjoint):
    short* xh    = (short*)xn;                          // after router GEMM1
    short* xl    = (short*)h;                           // after router GEMM2
    short* amanb = (short*)scores;                      // 32 MB, after topk
    short* w1h   = (short*)((char*)scores + (32u << 20));  // 8 MB
    short* w1l   = (short*)((char*)scores + (40u << 20));  // 8 MB
    short* w2b   = (short*)z;                           // 8 MB, after manifold

    // 1. x_norm = LN(x)
    ln_kernel<<<T_TOKENS, 256, 0, stream>>>(x, ln_w, ln_b, xn);
    // 2. h = gelu(xn @ Wr1^T)   (fp32 + libm erff — bitwise stable for top-k)
    gemm_f32_128<<<dim3(DM / 128, T_TOKENS / 128), 256, 0, stream>>>(xn, Wr1, h, T_TOKENS, DM, DM, 1);
    // 3. scores = h @ Wr2^T     (fp32)
    gemm_f32_128<<<dim3(DF / 128, T_TOKENS / 128), 256, 0, stream>>>(h, Wr2, scores, T_TOKENS, DF, DM, 0);
    // 4. top_idx
    topk_kernel<<<T_TOKENS, 256, 0, stream>>>(scores, tidx);
    // 5. split x and W1 into bf16 planes
    cvt_split_kernel<<<(T_TOKENS * DM / 4 + 255) / 256, 256, 0, stream>>>(x, xh, xl, T_TOKENS * DM / 4);
    cvt_split_kernel<<<(DF * DM / 4 + 255) / 256, 256, 0, stream>>>(W1, w1h, w1l, DF * DM / 4);
    // 6. z = x @ W1^T via 3-pass split-bf16 MFMA
    gemm_bf16<<<dim3(DF / 128, T_TOKENS / 128), 256, 0, stream>>>(xh, w1h, z, T_TOKENS, DF, DM, 0);
    gemm_bf16<<<dim3(DF / 128, T_TOKENS / 128), 256, 0, stream>>>(xh, w1l, z, T_TOKENS, DF, DM, 1);
    gemm_bf16<<<dim3(DF / 128, T_TOKENS / 128), 256, 0, stream>>>(xl, w1h, z, T_TOKENS, DF, DM, 1);
    // 7. manifold (fast erf, arch-VGPR arrays)
    manifold_kernel<<<T_TOKENS, 256, 0, stream>>>(z, tidx, phi1_w, phi1_b, pl1w, pl1b,
                                                  phi2_w, phi2_b, pl2w, pl2b,
                                                  rho1_w, rho1_b, rho2_w, rho2_b, man);
    // 8. scatter man -> bf16 a_man; W2 -> bf16
    hipMemsetAsync(amanb, 0, sizeof(short) * (size_t)T_TOKENS * DF, stream);
    scatter_bf16_kernel<<<T_TOKENS, 256, 0, stream>>>(man, tidx, amanb);
    cvt_bf16_kernel<<<(DM * DF / 4 + 255) / 256, 256, 0, stream>>>(W2, w2b, DM * DF / 4);
    // 9. out = a_man @ W2^T  (plain bf16 MFMA)
    gemm_bf16<<<dim3(DM / 128, T_TOKENS / 128), 256, 0, stream>>>(amanb, w2b, out, T_TOKENS, DM, DF, 0);
}

// Round 6
// 1275.818 us; speedup vs baseline: 1.1810x; 1.1810x over previous
//
#include <hip/hip_runtime.h>

#define T_TOKENS 4096
#define DM 1024
#define DF 4096
#define KSEL 256
#define DH 64
#define DH2 32

typedef __attribute__((ext_vector_type(8))) short short8;
typedef __attribute__((ext_vector_type(4))) float f32x4;
typedef __attribute__((ext_vector_type(2))) float f32x2;

__device__ __forceinline__ f32x2 pkfma(f32x2 a, f32x2 b, f32x2 c) {
    return __builtin_elementwise_fma(a, b, c);  // -> v_pk_fma_f32
}

// exact-libm gelu: ONLY for the router path (scores must stay bitwise stable)
__device__ __forceinline__ float gelu_f(float x) {
    return 0.5f * x * (1.0f + erff(x * 0.70710678118654752440f));
}

// branch-free erf, Abramowitz-Stegun 7.1.26, |err| <= 1.5e-7 abs
__device__ __forceinline__ float erf_fast(float x) {
    float ax = __builtin_fabsf(x);
    float t = __builtin_amdgcn_rcpf(fmaf(0.3275911f, ax, 1.0f));
    float p = 1.061405429f;
    p = fmaf(p, t, -1.453152027f);
    p = fmaf(p, t, 1.421413741f);
    p = fmaf(p, t, -0.284496736f);
    p = fmaf(p, t, 0.254829592f);
    float e = __builtin_amdgcn_exp2f(-ax * ax * 1.44269504088896f);
    float r = fmaf(-p * t, e, 1.0f);
    return __builtin_copysignf(r, x);
}
__device__ __forceinline__ float gelu_fast(float x) {
    return 0.5f * x * (1.0f + erf_fast(x * 0.70710678118654752440f));
}

__device__ __forceinline__ unsigned short bf16_rne(float f) {
    unsigned u = __float_as_uint(f);
    unsigned r = (u + 0x7FFFu + ((u >> 16) & 1u)) >> 16;
    return (unsigned short)r;
}
__device__ __forceinline__ float bf16_to_f(unsigned short h) {
    return __uint_as_float(((unsigned)h) << 16);
}

// ---------------- LayerNorm over last dim (1024), one block per row ----------------
__global__ __launch_bounds__(256) void ln_kernel(const float* __restrict__ x,
                                                 const float* __restrict__ w,
                                                 const float* __restrict__ b,
                                                 float* __restrict__ out) {
    int row = blockIdx.x;
    int tid = threadIdx.x;
    const float4 v = ((const float4*)(x + (size_t)row * DM))[tid];
    float s = v.x + v.y + v.z + v.w;
    float s2 = v.x * v.x + v.y * v.y + v.z * v.z + v.w * v.w;
#pragma unroll
    for (int off = 32; off > 0; off >>= 1) {
        s += __shfl_xor(s, off);
        s2 += __shfl_xor(s2, off);
    }
    __shared__ float ss[4], ss2[4];
    int wave = tid >> 6;
    if ((tid & 63) == 0) { ss[wave] = s; ss2[wave] = s2; }
    __syncthreads();
    s = ss[0] + ss[1] + ss[2] + ss[3];
    s2 = ss2[0] + ss2[1] + ss2[2] + ss2[3];
    float mu = s * (1.0f / DM);
    float var = s2 * (1.0f / DM) - mu * mu;
    float rs = rsqrtf(var + 1e-5f);
    const float4 wv = ((const float4*)w)[tid];
    const float4 bv = ((const float4*)b)[tid];
    float4 o;
    o.x = (v.x - mu) * rs * wv.x + bv.x;
    o.y = (v.y - mu) * rs * wv.y + bv.y;
    o.z = (v.z - mu) * rs * wv.z + bv.z;
    o.w = (v.w - mu) * rs * wv.w + bv.w;
    ((float4*)(out + (size_t)row * DM))[tid] = o;
}

// ---------------- fp32 GEMM (router): C = A[M,K]*B[N,K]^T, 128x128, 8x8 micro ------
// Per-element k-accumulation order bitwise stable across rounds -> top-k safe.
__global__ __launch_bounds__(256) void gemm_f32_128(const float* __restrict__ A,
                                                    const float* __restrict__ B,
                                                    float* __restrict__ C,
                                                    int M, int N, int K, int fuse_gelu) {
    __shared__ __align__(16) float As[16][132];
    __shared__ __align__(16) float Bs[16][132];
    int tid = threadIdx.x;
    int bm = blockIdx.y * 128, bn = blockIdx.x * 128;
    int tr = tid >> 4, tc = tid & 15;

    float4 avr[2], bvr[2];
    auto g_load = [&](int k0) {
#pragma unroll
        for (int s = 0; s < 2; s++) {
            int i = tid * 2 + s;
            int r = i >> 2, q = i & 3;
            avr[s] = *(const float4*)(A + (size_t)(bm + r) * K + k0 + q * 4);
            bvr[s] = *(const float4*)(B + (size_t)(bn + r) * K + k0 + q * 4);
        }
    };

    float acc[8][8] = {};
    g_load(0);
    for (int k0 = 0; k0 < K; k0 += 16) {
        __syncthreads();
#pragma unroll
        for (int s = 0; s < 2; s++) {
            int i = tid * 2 + s;
            int r = i >> 2, q = i & 3;
            As[q * 4 + 0][r] = avr[s].x; As[q * 4 + 1][r] = avr[s].y;
            As[q * 4 + 2][r] = avr[s].z; As[q * 4 + 3][r] = avr[s].w;
            Bs[q * 4 + 0][r] = bvr[s].x; Bs[q * 4 + 1][r] = bvr[s].y;
            Bs[q * 4 + 2][r] = bvr[s].z; Bs[q * 4 + 3][r] = bvr[s].w;
        }
        __syncthreads();
        if (k0 + 16 < K) g_load(k0 + 16);
#pragma unroll
        for (int kk = 0; kk < 16; kk++) {
            float4 a0 = *(const float4*)&As[kk][tr * 8];
            float4 a1 = *(const float4*)&As[kk][tr * 8 + 4];
            float4 b0 = *(const float4*)&Bs[kk][tc * 8];
            float4 b1 = *(const float4*)&Bs[kk][tc * 8 + 4];
            float ar[8] = {a0.x, a0.y, a0.z, a0.w, a1.x, a1.y, a1.z, a1.w};
            float br[8] = {b0.x, b0.y, b0.z, b0.w, b1.x, b1.y, b1.z, b1.w};
#pragma unroll
            for (int i = 0; i < 8; i++)
#pragma unroll
                for (int j = 0; j < 8; j++)
                    acc[i][j] = fmaf(ar[i], br[j], acc[i][j]);
        }
    }
#pragma unroll
    for (int i = 0; i < 8; i++) {
        float* cp = C + (size_t)(bm + tr * 8 + i) * N + bn + tc * 8;
        float4 o0, o1;
        if (fuse_gelu) {
            o0 = make_float4(gelu_f(acc[i][0]), gelu_f(acc[i][1]), gelu_f(acc[i][2]), gelu_f(acc[i][3]));
            o1 = make_float4(gelu_f(acc[i][4]), gelu_f(acc[i][5]), gelu_f(acc[i][6]), gelu_f(acc[i][7]));
        } else {
            o0 = make_float4(acc[i][0], acc[i][1], acc[i][2], acc[i][3]);
            o1 = make_float4(acc[i][4], acc[i][5], acc[i][6], acc[i][7]);
        }
        ((float4*)cp)[0] = o0;
        ((float4*)cp)[1] = o1;
    }
}

// ---------------- bf16 MFMA GEMM: C[M,N] (+)= A[M,K]*B[N,K]^T, strided rows -------
__global__ __launch_bounds__(256) void gemm_bf16(const short* __restrict__ A,
                                                 const short* __restrict__ B,
                                                 float* __restrict__ C,
                                                 int M, int N, int K,
                                                 int lda, int ldb, int beta) {
    __shared__ __align__(16) short As[128 * 64];
    __shared__ __align__(16) short Bs[128 * 64];
    int tid = threadIdx.x;
    int bm = blockIdx.y * 128, bn = blockIdx.x * 128;
    int lane = tid & 63, wave = tid >> 6;
    int wm = (wave >> 1) * 64, wn = (wave & 1) * 64;
    int quad = lane >> 4, l16 = lane & 15;
    int sr = tid >> 3, scp = tid & 7;

    short8 areg[4], breg[4];
    auto g_load = [&](int k0) {
#pragma unroll
        for (int j = 0; j < 4; j++) {
            int r = j * 32 + sr;
            int cl = scp ^ (r & 7);
            areg[j] = *(const short8*)(A + (size_t)(bm + r) * lda + k0 + cl * 8);
            breg[j] = *(const short8*)(B + (size_t)(bn + r) * ldb + k0 + cl * 8);
        }
    };

    f32x4 acc[4][4] = {};
    g_load(0);
    for (int k0 = 0; k0 < K; k0 += 64) {
        __syncthreads();
#pragma unroll
        for (int j = 0; j < 4; j++) {
            *(short8*)(As + (j * 256 + tid) * 8) = areg[j];
            *(short8*)(Bs + (j * 256 + tid) * 8) = breg[j];
        }
        __syncthreads();
        if (k0 + 64 < K) g_load(k0 + 64);
#pragma unroll
        for (int kk = 0; kk < 2; kk++) {
            short8 af[4], bf[4];
#pragma unroll
            for (int tm = 0; tm < 4; tm++) {
                int m = wm + tm * 16 + l16;
                int cp = (kk * 4 + quad) ^ (m & 7);
                af[tm] = *(const short8*)(As + m * 64 + cp * 8);
            }
#pragma unroll
            for (int tn = 0; tn < 4; tn++) {
                int n = wn + tn * 16 + l16;
                int cp = (kk * 4 + quad) ^ (n & 7);
                bf[tn] = *(const short8*)(Bs + n * 64 + cp * 8);
            }
#pragma unroll
            for (int tm = 0; tm < 4; tm++)
#pragma unroll
                for (int tn = 0; tn < 4; tn++)
                    acc[tm][tn] = __builtin_amdgcn_mfma_f32_16x16x32_bf16(
                        af[tm], bf[tn], acc[tm][tn], 0, 0, 0);
        }
    }
#pragma unroll
    for (int tm = 0; tm < 4; tm++)
#pragma unroll
        for (int tn = 0; tn < 4; tn++) {
            int row0 = bm + wm + tm * 16 + quad * 4;
            int col = bn + wn + tn * 16 + l16;
#pragma unroll
            for (int r = 0; r < 4; r++) {
                float* p = C + (size_t)(row0 + r) * N + col;
                float v = acc[tm][tn][r];
                if (beta) v += *p;
                *p = v;
            }
        }
}

// ---------------- fp32 -> concatenated (hi|lo) or (lo|hi) bf16 planes -------------
// out row length = 2*cols shorts; plane A at [row*2c .. +c), plane B at [+c .. +2c)
__global__ __launch_bounds__(256) void cvt_split_cat_kernel(const float* __restrict__ x,
                                                            short* __restrict__ cat,
                                                            int n4, int lo_first) {
    int i = blockIdx.x * 256 + threadIdx.x;
    if (i >= n4) return;
    float4 v = ((const float4*)x)[i];
    ushort4 h, l;
    h.x = bf16_rne(v.x); l.x = bf16_rne(v.x - bf16_to_f(h.x));
    h.y = bf16_rne(v.y); l.y = bf16_rne(v.y - bf16_to_f(h.y));
    h.z = bf16_rne(v.z); l.z = bf16_rne(v.z - bf16_to_f(h.z));
    h.w = bf16_rne(v.w); l.w = bf16_rne(v.w - bf16_to_f(h.w));
    int row = i >> 8;            // DM/4 = 256 float4 per row
    int col4 = i & 255;
    size_t base = (size_t)row * (2 * DM);
    size_t off_a = base + col4 * 4;
    size_t off_b = base + DM + col4 * 4;
    ((ushort4*)(cat + (lo_first ? off_b : off_a)))[0] = h;
    ((ushort4*)(cat + (lo_first ? off_a : off_b)))[0] = l;
}

__global__ __launch_bounds__(256) void cvt_bf16_kernel(const float* __restrict__ x,
                                                       short* __restrict__ y, int n4) {
    int i = blockIdx.x * 256 + threadIdx.x;
    if (i >= n4) return;
    float4 v = ((const float4*)x)[i];
    ushort4 h;
    h.x = bf16_rne(v.x); h.y = bf16_rne(v.y);
    h.z = bf16_rne(v.z); h.w = bf16_rne(v.w);
    ((ushort4*)y)[i] = h;
}

// ---------------- top-k (k=256 of 4096) per row, exact tie-break ------------------
__device__ __forceinline__ unsigned sortable(float f) {
    unsigned u = __float_as_uint(f);
    return (u & 0x80000000u) ? ~u : (u | 0x80000000u);
}

__global__ __launch_bounds__(256) void topk_kernel(const float* __restrict__ scores,
                                                   int* __restrict__ top_idx) {
    int row = blockIdx.x;
    int tid = threadIdx.x;
    __shared__ unsigned s_keys[DF];
    __shared__ int hist[256];
    __shared__ int sufs[256];
    __shared__ int s_misc[4];
    __shared__ int s_wsums[4];

    const float* sr = scores + (size_t)row * DF;
    for (int i = tid; i < DF; i += 256) s_keys[i] = sortable(sr[i]);

    unsigned prefix = 0;
    int krem = KSEL;
    for (int pass = 0; pass < 4; pass++) {
        int shift = 24 - pass * 8;
        unsigned hmask = (pass == 0) ? 0u : (0xFFFFFFFFu << (shift + 8));
        hist[tid] = 0;
        __syncthreads();
        for (int i = tid; i < DF; i += 256) {
            unsigned u = s_keys[i];
            if ((u & hmask) == prefix) atomicAdd(&hist[(u >> shift) & 0xFF], 1);
        }
        __syncthreads();
        sufs[tid] = hist[tid];
        __syncthreads();
#pragma unroll
        for (int off = 1; off < 256; off <<= 1) {
            int add = (tid + off < 256) ? sufs[tid + off] : 0;
            __syncthreads();
            sufs[tid] += add;
            __syncthreads();
        }
        if (sufs[tid] >= krem && (tid == 255 || sufs[tid + 1] < krem)) {
            s_misc[0] = tid;
            s_misc[1] = sufs[tid] - hist[tid];
        }
        __syncthreads();
        prefix |= ((unsigned)s_misc[0]) << shift;
        krem -= s_misc[1];
        __syncthreads();
    }
    unsigned v = prefix;
    if (tid == 0) s_misc[2] = 0;
    __syncthreads();
    int* out = top_idx + (size_t)row * KSEL;
    for (int i = tid; i < DF; i += 256) {
        if (s_keys[i] > v) {
            int p = atomicAdd(&s_misc[2], 1);
            out[p] = i;
        }
    }
    __syncthreads();
    int base = s_misc[2];
    int lane = tid & 63, wave = tid >> 6;
    int taken = 0;
    for (int chunk = 0; chunk < DF / 256; chunk++) {
        int i = chunk * 256 + tid;
        int flag = (s_keys[i] == v) ? 1 : 0;
        unsigned long long mb = __ballot(flag);
        int before = __popcll(mb & ((1ULL << lane) - 1ULL));
        if (lane == 0) s_wsums[wave] = __popcll(mb);
        __syncthreads();
        int woff = 0;
#pragma unroll
        for (int w = 0; w < 4; w++) if (w < wave) woff += s_wsums[w];
        int total = s_wsums[0] + s_wsums[1] + s_wsums[2] + s_wsums[3];
        int excl = woff + before;
        if (flag && (taken + excl) < krem) out[base + taken + excl] = i;
        taken += total;
        __syncthreads();
    }
}

// ---------------- DeepSets manifold: one block per token, one k per thread --------
// Hot dots in f32x2 via v_pk_fma_f32 (2 FMA/instr): halves rho1/phi2 issue count.
// Default launch bounds (round-4 config: ~3.4 waves/SIMD was the best point).
__global__ __launch_bounds__(256) void manifold_kernel(
    const float* __restrict__ z, const int* __restrict__ top_idx,
    const float* __restrict__ phi1_w, const float* __restrict__ phi1_b,
    const float* __restrict__ ln1w, const float* __restrict__ ln1b,
    const float* __restrict__ phi2_w, const float* __restrict__ phi2_b,
    const float* __restrict__ ln2w, const float* __restrict__ ln2b,
    const float* __restrict__ rho1_w, const float* __restrict__ rho1_b,
    const float* __restrict__ rho2_w, const float* __restrict__ rho2_b,
    float* __restrict__ man) {
    __shared__ float s_ctxp[4 * DH];
    __shared__ float s_ctx[DH];

    int tid = threadIdx.x;
    int t = blockIdx.x;
    int lane = tid & 63, wave = tid >> 6;

    int idx = top_idx[(size_t)t * KSEL + tid];
    float a = gelu_fast(z[(size_t)t * DF + idx]);
    f32x2 a2 = {a, a};

    // --- e = a*phi1_w + phi1_b (pairs); LN over 32; g = gelu(LN(e)) ---
    f32x2 gv[DH2 / 2];
    f32x2 sv = {0.f, 0.f}, qv = {0.f, 0.f};
#pragma unroll
    for (int i = 0; i < DH2 / 2; i++) {
        f32x2 w = ((const f32x2*)phi1_w)[i];
        f32x2 b = ((const f32x2*)phi1_b)[i];
        f32x2 e = pkfma(a2, w, b);
        gv[i] = e;
        sv = sv + e;
        qv = pkfma(e, e, qv);
    }
    float s = sv.x + sv.y, s2 = qv.x + qv.y;
    float mu = s * (1.0f / DH2);
    float rs = rsqrtf(s2 * (1.0f / DH2) - mu * mu + 1e-5f);
    f32x2 muv = {mu, mu}, rsv = {rs, rs};
#pragma unroll
    for (int i = 0; i < DH2 / 2; i++) {
        f32x2 t2 = (gv[i] - muv) * rsv;
        t2 = pkfma(t2, ((const f32x2*)ln1w)[i], ((const f32x2*)ln1b)[i]);
        gv[i] = (f32x2){gelu_fast(t2.x), gelu_fast(t2.y)};
    }

    // --- h[j] = phi2_b[j] + g . phi2_w[j,:]  (16 pk-fma per j) ---
    f32x2 hv[DH / 2];
#pragma unroll
    for (int j2 = 0; j2 < DH / 2; j2++) {
        const f32x2* wa = (const f32x2*)(phi2_w + (2 * j2) * DH2);
        const f32x2* wb = (const f32x2*)(phi2_w + (2 * j2 + 1) * DH2);
        f32x2 ra = {phi2_b[2 * j2], 0.f};
        f32x2 rb = {phi2_b[2 * j2 + 1], 0.f};
#pragma unroll
        for (int i = 0; i < DH2 / 2; i++) {
            ra = pkfma(gv[i], wa[i], ra);
            rb = pkfma(gv[i], wb[i], rb);
        }
        hv[j2] = (f32x2){ra.x + ra.y, rb.x + rb.y};
    }

    // --- LN over 64 (pairs) ---
    f32x2 tsv = {0.f, 0.f}, tqv = {0.f, 0.f};
#pragma unroll
    for (int j2 = 0; j2 < DH / 2; j2++) {
        tsv = tsv + hv[j2];
        tqv = pkfma(hv[j2], hv[j2], tqv);
    }
    float tsum = tsv.x + tsv.y, tsq = tqv.x + tqv.y;
    float mu2 = tsum * (1.0f / DH);
    float rs2 = rsqrtf(tsq * (1.0f / DH) - mu2 * mu2 + 1e-5f);
    f32x2 mu2v = {mu2, mu2}, rs2v = {rs2, rs2};
#pragma unroll
    for (int j2 = 0; j2 < DH / 2; j2++) {
        f32x2 t2 = (hv[j2] - mu2v) * rs2v;
        hv[j2] = pkfma(t2, ((const f32x2*)ln2w)[j2], ((const f32x2*)ln2b)[j2]);
    }

    // --- ctx = mean over k: per-reg wave butterfly, then cross-wave ---
#pragma unroll
    for (int j2 = 0; j2 < DH / 2; j2++) {
        float vx = hv[j2].x, vy = hv[j2].y;
#pragma unroll
        for (int st = 1; st < 64; st <<= 1) {
            vx += __shfl_xor(vx, st);
            vy += __shfl_xor(vy, st);
        }
        if (lane == 0) {
            s_ctxp[wave * DH + 2 * j2] = vx;
            s_ctxp[wave * DH + 2 * j2 + 1] = vy;
        }
    }
    __syncthreads();
    if (tid < DH)
        s_ctx[tid] = (s_ctxp[tid] + s_ctxp[DH + tid] + s_ctxp[2 * DH + tid] +
                      s_ctxp[3 * DH + tid]) * (1.0f / KSEL);
    __syncthreads();

    // --- c = e64 + ctx; man = gelu(c @ rho1^T + b1) @ rho2^T + b2 ---
#pragma unroll
    for (int j2 = 0; j2 < DH / 2; j2++) hv[j2] = hv[j2] + ((const f32x2*)s_ctx)[j2];
    float m = rho2_b[0];
    for (int p = 0; p < 2 * DH; p++) {
        const f32x2* wp = (const f32x2*)(rho1_w + p * DH);
        f32x2 r0 = {rho1_b[p], 0.f};
        f32x2 r1 = {0.f, 0.f};
#pragma unroll
        for (int q2 = 0; q2 < DH / 2; q2 += 2) {
            r0 = pkfma(hv[q2], wp[q2], r0);
            r1 = pkfma(hv[q2 + 1], wp[q2 + 1], r1);
        }
        float r = (r0.x + r0.y) + (r1.x + r1.y);
        m = fmaf(gelu_fast(r), rho2_w[p], m);
    }
    man[(size_t)t * KSEL + tid] = m;
}

// ---------------- scatter man (as bf16) into zeroed bf16 a_man --------------------
__global__ __launch_bounds__(256) void scatter_bf16_kernel(const float* __restrict__ man,
                                                           const int* __restrict__ top_idx,
                                                           short* __restrict__ a_man) {
    int t = blockIdx.x, k = threadIdx.x;
    a_man[(size_t)t * DF + top_idx[(size_t)t * KSEL + k]] =
        (short)bf16_rne(man[(size_t)t * KSEL + k]);
}

extern "C" void kernel_launch(void* const* d_in, const int* in_sizes, int n_in,
                              void* d_out, int out_size, void* d_ws, size_t ws_size,
                              hipStream_t stream) {
    const float* x      = (const float*)d_in[0];
    const float* W1     = (const float*)d_in[1];
    const float* W2     = (const float*)d_in[2];
    const float* Wr1    = (const float*)d_in[3];
    const float* Wr2    = (const float*)d_in[4];
    const float* ln_w   = (const float*)d_in[5];
    const float* ln_b   = (const float*)d_in[6];
    const float* phi1_w = (const float*)d_in[7];
    const float* phi1_b = (const float*)d_in[8];
    const float* pl1w   = (const float*)d_in[9];
    const float* pl1b   = (const float*)d_in[10];
    const float* phi2_w = (const float*)d_in[11];
    const float* phi2_b = (const float*)d_in[12];
    const float* pl2w   = (const float*)d_in[13];
    const float* pl2b   = (const float*)d_in[14];
    const float* rho1_w = (const float*)d_in[15];
    const float* rho1_b = (const float*)d_in[16];
    const float* rho2_w = (const float*)d_in[17];
    const float* rho2_b = (const float*)d_in[18];
    float* out = (float*)d_out;

    char* ws = (char*)d_ws;
    size_t off = 0;
    auto alloc = [&](size_t bytes) {
        char* p = ws + off;
        off += (bytes + 255) & ~(size_t)255;
        return p;
    };
    float* xn     = (float*)alloc(sizeof(float) * (size_t)T_TOKENS * DM);   // 16 MB
    float* h      = (float*)alloc(sizeof(float) * (size_t)T_TOKENS * DM);   // 16 MB
    float* scores = (float*)alloc(sizeof(float) * (size_t)T_TOKENS * DF);   // 64 MB
    float* z      = (float*)alloc(sizeof(float) * (size_t)T_TOKENS * DF);   // 64 MB
    int*   tidx   = (int*)alloc(sizeof(int) * (size_t)T_TOKENS * KSEL);     // 4 MB
    float* man    = (float*)alloc(sizeof(float) * (size_t)T_TOKENS * KSEL); // 4 MB

    // Region reuse (stream-serial, lifetimes disjoint):
    short* xcat  = (short*)xn;      // [4096 x 2048] = 16 MB: [xh | xl], after GEMM1
    short* w1cat = (short*)h;       // [4096 x 2048] = 16 MB: [w1l | w1h], after GEMM2
    short* amanb = (short*)scores;  // 32 MB, after topk
    short* w2b   = (short*)z;       // 8 MB, after manifold

    // 1. x_norm = LN(x)
    ln_kernel<<<T_TOKENS, 256, 0, stream>>>(x, ln_w, ln_b, xn);
    // 2. h = gelu(xn @ Wr1^T)   (fp32 + libm erff — bitwise stable for top-k)
    gemm_f32_128<<<dim3(DM / 128, T_TOKENS / 128), 256, 0, stream>>>(xn, Wr1, h, T_TOKENS, DM, DM, 1);
    // 3. scores = h @ Wr2^T     (fp32)
    gemm_f32_128<<<dim3(DF / 128, T_TOKENS / 128), 256, 0, stream>>>(h, Wr2, scores, T_TOKENS, DF, DM, 0);
    // 4. top_idx
    topk_kernel<<<T_TOKENS, 256, 0, stream>>>(scores, tidx);
    // 5. split x -> [xh|xl], W1 -> [w1l|w1h]
    cvt_split_cat_kernel<<<(T_TOKENS * DM / 4 + 255) / 256, 256, 0, stream>>>(x, xcat, T_TOKENS * DM / 4, 0);
    cvt_split_cat_kernel<<<(DF * DM / 4 + 255) / 256, 256, 0, stream>>>(W1, w1cat, DF * DM / 4, 1);
    // 6. z = x @ W1^T: hi*hi (K=1024) + merged cross terms (K=2048)
    gemm_bf16<<<dim3(DF / 128, T_TOKENS / 128), 256, 0, stream>>>(
        xcat, w1cat + DM, z, T_TOKENS, DF, DM, 2 * DM, 2 * DM, 0);
    gemm_bf16<<<dim3(DF / 128, T_TOKENS / 128), 256, 0, stream>>>(
        xcat, w1cat, z, T_TOKENS, DF, 2 * DM, 2 * DM, 2 * DM, 1);
    // 7. manifold (pk-fma)
    manifold_kernel<<<T_TOKENS, 256, 0, stream>>>(z, tidx, phi1_w, phi1_b, pl1w, pl1b,
                                                  phi2_w, phi2_b, pl2w, pl2b,
                                                  rho1_w, rho1_b, rho2_w, rho2_b, man);
    // 8. scatter man -> bf16 a_man; W2 -> bf16
    hipMemsetAsync(amanb, 0, sizeof(short) * (size_t)T_TOKENS * DF, stream);
    scatter_bf16_kernel<<<T_TOKENS, 256, 0, stream>>>(man, tidx, amanb);
    cvt_bf16_kernel<<<(DM * DF / 4 + 255) / 256, 256, 0, stream>>>(W2, w2b, DM * DF / 4);
    // 9. out = a_man @ W2^T  (plain bf16 MFMA)
    gemm_bf16<<<dim3(DM / 128, T_TOKENS / 128), 256, 0, stream>>>(
        amanb, w2b, out, T_TOKENS, DM, DF, DF, DF, 0);
}

// Round 7
// 1211.470 us; speedup vs baseline: 1.2437x; 1.0531x over previous
//
#include <hip/hip_runtime.h>

#define T_TOKENS 4096
#define DM 1024
#define DF 4096
#define KSEL 256
#define DH 64
#define DH2 32

typedef __attribute__((ext_vector_type(8))) short short8;
typedef __attribute__((ext_vector_type(4))) float f32x4;
typedef __attribute__((ext_vector_type(2))) float f32x2;

__device__ __forceinline__ f32x2 pkfma(f32x2 a, f32x2 b, f32x2 c) {
    return __builtin_elementwise_fma(a, b, c);  // -> v_pk_fma_f32
}

// exact-libm gelu: ONLY for the router path (scores must stay bitwise stable)
__device__ __forceinline__ float gelu_f(float x) {
    return 0.5f * x * (1.0f + erff(x * 0.70710678118654752440f));
}

// branch-free erf, Abramowitz-Stegun 7.1.26, |err| <= 1.5e-7 abs
__device__ __forceinline__ float erf_fast(float x) {
    float ax = __builtin_fabsf(x);
    float t = __builtin_amdgcn_rcpf(fmaf(0.3275911f, ax, 1.0f));
    float p = 1.061405429f;
    p = fmaf(p, t, -1.453152027f);
    p = fmaf(p, t, 1.421413741f);
    p = fmaf(p, t, -0.284496736f);
    p = fmaf(p, t, 0.254829592f);
    float e = __builtin_amdgcn_exp2f(-ax * ax * 1.44269504088896f);
    float r = fmaf(-p * t, e, 1.0f);
    return __builtin_copysignf(r, x);
}
__device__ __forceinline__ float gelu_fast(float x) {
    return 0.5f * x * (1.0f + erf_fast(x * 0.70710678118654752440f));
}

__device__ __forceinline__ unsigned short bf16_rne(float f) {
    unsigned u = __float_as_uint(f);
    unsigned r = (u + 0x7FFFu + ((u >> 16) & 1u)) >> 16;
    return (unsigned short)r;
}
__device__ __forceinline__ float bf16_to_f(unsigned short h) {
    return __uint_as_float(((unsigned)h) << 16);
}

// ---------------- LayerNorm over last dim (1024), one block per row ----------------
__global__ __launch_bounds__(256) void ln_kernel(const float* __restrict__ x,
                                                 const float* __restrict__ w,
                                                 const float* __restrict__ b,
                                                 float* __restrict__ out) {
    int row = blockIdx.x;
    int tid = threadIdx.x;
    const float4 v = ((const float4*)(x + (size_t)row * DM))[tid];
    float s = v.x + v.y + v.z + v.w;
    float s2 = v.x * v.x + v.y * v.y + v.z * v.z + v.w * v.w;
#pragma unroll
    for (int off = 32; off > 0; off >>= 1) {
        s += __shfl_xor(s, off);
        s2 += __shfl_xor(s2, off);
    }
    __shared__ float ss[4], ss2[4];
    int wave = tid >> 6;
    if ((tid & 63) == 0) { ss[wave] = s; ss2[wave] = s2; }
    __syncthreads();
    s = ss[0] + ss[1] + ss[2] + ss[3];
    s2 = ss2[0] + ss2[1] + ss2[2] + ss2[3];
    float mu = s * (1.0f / DM);
    float var = s2 * (1.0f / DM) - mu * mu;
    float rs = rsqrtf(var + 1e-5f);
    const float4 wv = ((const float4*)w)[tid];
    const float4 bv = ((const float4*)b)[tid];
    float4 o;
    o.x = (v.x - mu) * rs * wv.x + bv.x;
    o.y = (v.y - mu) * rs * wv.y + bv.y;
    o.z = (v.z - mu) * rs * wv.z + bv.z;
    o.w = (v.w - mu) * rs * wv.w + bv.w;
    ((float4*)(out + (size_t)row * DM))[tid] = o;
}

// ---------------- fp32 GEMM (router): C = A[M,K]*B[N,K]^T, 128x128, 8x8 micro ------
// 4+4 split microtile: thread owns cols {tc*4..+3, 64+tc*4..+3}, rows likewise.
// B-fragment ds_read_b128 banks = tc*4%32 -> only 2-way aliasing (free, m136);
// old tc*8 layout was 4-way conflicted (4.2e7 conflict cycles/dispatch).
// Per-element k-accumulation order unchanged -> scores bitwise stable -> top-k safe.
__global__ __launch_bounds__(256) void gemm_f32_128(const float* __restrict__ A,
                                                    const float* __restrict__ B,
                                                    float* __restrict__ C,
                                                    int M, int N, int K, int fuse_gelu) {
    __shared__ __align__(16) float As[16][132];
    __shared__ __align__(16) float Bs[16][132];
    int tid = threadIdx.x;
    int bm = blockIdx.y * 128, bn = blockIdx.x * 128;
    int tr = tid >> 4, tc = tid & 15;

    float4 avr[2], bvr[2];
    auto g_load = [&](int k0) {
#pragma unroll
        for (int s = 0; s < 2; s++) {
            int i = tid * 2 + s;
            int r = i >> 2, q = i & 3;
            avr[s] = *(const float4*)(A + (size_t)(bm + r) * K + k0 + q * 4);
            bvr[s] = *(const float4*)(B + (size_t)(bn + r) * K + k0 + q * 4);
        }
    };

    float acc[8][8] = {};
    g_load(0);
    for (int k0 = 0; k0 < K; k0 += 16) {
        __syncthreads();
#pragma unroll
        for (int s = 0; s < 2; s++) {
            int i = tid * 2 + s;
            int r = i >> 2, q = i & 3;
            As[q * 4 + 0][r] = avr[s].x; As[q * 4 + 1][r] = avr[s].y;
            As[q * 4 + 2][r] = avr[s].z; As[q * 4 + 3][r] = avr[s].w;
            Bs[q * 4 + 0][r] = bvr[s].x; Bs[q * 4 + 1][r] = bvr[s].y;
            Bs[q * 4 + 2][r] = bvr[s].z; Bs[q * 4 + 3][r] = bvr[s].w;
        }
        __syncthreads();
        if (k0 + 16 < K) g_load(k0 + 16);
#pragma unroll
        for (int kk = 0; kk < 16; kk++) {
            float4 a0 = *(const float4*)&As[kk][tr * 4];
            float4 a1 = *(const float4*)&As[kk][64 + tr * 4];
            float4 b0 = *(const float4*)&Bs[kk][tc * 4];
            float4 b1 = *(const float4*)&Bs[kk][64 + tc * 4];
            float ar[8] = {a0.x, a0.y, a0.z, a0.w, a1.x, a1.y, a1.z, a1.w};
            float br[8] = {b0.x, b0.y, b0.z, b0.w, b1.x, b1.y, b1.z, b1.w};
#pragma unroll
            for (int i = 0; i < 8; i++)
#pragma unroll
                for (int j = 0; j < 8; j++)
                    acc[i][j] = fmaf(ar[i], br[j], acc[i][j]);
        }
    }
#pragma unroll
    for (int i = 0; i < 8; i++) {
        int row = bm + (i < 4 ? tr * 4 + i : 64 + tr * 4 + (i - 4));
        float* cp = C + (size_t)row * N + bn;
        float4 o0, o1;
        if (fuse_gelu) {
            o0 = make_float4(gelu_f(acc[i][0]), gelu_f(acc[i][1]), gelu_f(acc[i][2]), gelu_f(acc[i][3]));
            o1 = make_float4(gelu_f(acc[i][4]), gelu_f(acc[i][5]), gelu_f(acc[i][6]), gelu_f(acc[i][7]));
        } else {
            o0 = make_float4(acc[i][0], acc[i][1], acc[i][2], acc[i][3]);
            o1 = make_float4(acc[i][4], acc[i][5], acc[i][6], acc[i][7]);
        }
        *(float4*)(cp + tc * 4) = o0;
        *(float4*)(cp + 64 + tc * 4) = o1;
    }
}

// ---------------- bf16 MFMA GEMM: C[M,N] (+)= A[M,K]*B[N,K]^T, strided rows -------
__global__ __launch_bounds__(256) void gemm_bf16(const short* __restrict__ A,
                                                 const short* __restrict__ B,
                                                 float* __restrict__ C,
                                                 int M, int N, int K,
                                                 int lda, int ldb, int beta) {
    __shared__ __align__(16) short As[128 * 64];
    __shared__ __align__(16) short Bs[128 * 64];
    int tid = threadIdx.x;
    int bm = blockIdx.y * 128, bn = blockIdx.x * 128;
    int lane = tid & 63, wave = tid >> 6;
    int wm = (wave >> 1) * 64, wn = (wave & 1) * 64;
    int quad = lane >> 4, l16 = lane & 15;
    int sr = tid >> 3, scp = tid & 7;

    short8 areg[4], breg[4];
    auto g_load = [&](int k0) {
#pragma unroll
        for (int j = 0; j < 4; j++) {
            int r = j * 32 + sr;
            int cl = scp ^ (r & 7);
            areg[j] = *(const short8*)(A + (size_t)(bm + r) * lda + k0 + cl * 8);
            breg[j] = *(const short8*)(B + (size_t)(bn + r) * ldb + k0 + cl * 8);
        }
    };

    f32x4 acc[4][4] = {};
    g_load(0);
    for (int k0 = 0; k0 < K; k0 += 64) {
        __syncthreads();
#pragma unroll
        for (int j = 0; j < 4; j++) {
            *(short8*)(As + (j * 256 + tid) * 8) = areg[j];
            *(short8*)(Bs + (j * 256 + tid) * 8) = breg[j];
        }
        __syncthreads();
        if (k0 + 64 < K) g_load(k0 + 64);
#pragma unroll
        for (int kk = 0; kk < 2; kk++) {
            short8 af[4], bf[4];
#pragma unroll
            for (int tm = 0; tm < 4; tm++) {
                int m = wm + tm * 16 + l16;
                int cp = (kk * 4 + quad) ^ (m & 7);
                af[tm] = *(const short8*)(As + m * 64 + cp * 8);
            }
#pragma unroll
            for (int tn = 0; tn < 4; tn++) {
                int n = wn + tn * 16 + l16;
                int cp = (kk * 4 + quad) ^ (n & 7);
                bf[tn] = *(const short8*)(Bs + n * 64 + cp * 8);
            }
#pragma unroll
            for (int tm = 0; tm < 4; tm++)
#pragma unroll
                for (int tn = 0; tn < 4; tn++)
                    acc[tm][tn] = __builtin_amdgcn_mfma_f32_16x16x32_bf16(
                        af[tm], bf[tn], acc[tm][tn], 0, 0, 0);
        }
    }
#pragma unroll
    for (int tm = 0; tm < 4; tm++)
#pragma unroll
        for (int tn = 0; tn < 4; tn++) {
            int row0 = bm + wm + tm * 16 + quad * 4;
            int col = bn + wn + tn * 16 + l16;
#pragma unroll
            for (int r = 0; r < 4; r++) {
                float* p = C + (size_t)(row0 + r) * N + col;
                float v = acc[tm][tn][r];
                if (beta) v += *p;
                *p = v;
            }
        }
}

// ---------------- fp32 -> concatenated (hi|lo) or (lo|hi) bf16 planes -------------
__global__ __launch_bounds__(256) void cvt_split_cat_kernel(const float* __restrict__ x,
                                                            short* __restrict__ cat,
                                                            int n4, int lo_first) {
    int i = blockIdx.x * 256 + threadIdx.x;
    if (i >= n4) return;
    float4 v = ((const float4*)x)[i];
    ushort4 h, l;
    h.x = bf16_rne(v.x); l.x = bf16_rne(v.x - bf16_to_f(h.x));
    h.y = bf16_rne(v.y); l.y = bf16_rne(v.y - bf16_to_f(h.y));
    h.z = bf16_rne(v.z); l.z = bf16_rne(v.z - bf16_to_f(h.z));
    h.w = bf16_rne(v.w); l.w = bf16_rne(v.w - bf16_to_f(h.w));
    int row = i >> 8;            // DM/4 = 256 float4 per row
    int col4 = i & 255;
    size_t base = (size_t)row * (2 * DM);
    size_t off_a = base + col4 * 4;
    size_t off_b = base + DM + col4 * 4;
    ((ushort4*)(cat + (lo_first ? off_b : off_a)))[0] = h;
    ((ushort4*)(cat + (lo_first ? off_a : off_b)))[0] = l;
}

__global__ __launch_bounds__(256) void cvt_bf16_kernel(const float* __restrict__ x,
                                                       short* __restrict__ y, int n4) {
    int i = blockIdx.x * 256 + threadIdx.x;
    if (i >= n4) return;
    float4 v = ((const float4*)x)[i];
    ushort4 h;
    h.x = bf16_rne(v.x); h.y = bf16_rne(v.y);
    h.z = bf16_rne(v.z); h.w = bf16_rne(v.w);
    ((ushort4*)y)[i] = h;
}

// ---------------- top-k (k=256 of 4096) per row, exact tie-break ------------------
__device__ __forceinline__ unsigned sortable(float f) {
    unsigned u = __float_as_uint(f);
    return (u & 0x80000000u) ? ~u : (u | 0x80000000u);
}

__global__ __launch_bounds__(256) void topk_kernel(const float* __restrict__ scores,
                                                   int* __restrict__ top_idx) {
    int row = blockIdx.x;
    int tid = threadIdx.x;
    __shared__ unsigned s_keys[DF];
    __shared__ int hist[256];
    __shared__ int sufs[256];
    __shared__ int s_misc[4];
    __shared__ int s_wsums[4];

    const float* sr = scores + (size_t)row * DF;
    for (int i = tid; i < DF; i += 256) s_keys[i] = sortable(sr[i]);

    unsigned prefix = 0;
    int krem = KSEL;
    for (int pass = 0; pass < 4; pass++) {
        int shift = 24 - pass * 8;
        unsigned hmask = (pass == 0) ? 0u : (0xFFFFFFFFu << (shift + 8));
        hist[tid] = 0;
        __syncthreads();
        for (int i = tid; i < DF; i += 256) {
            unsigned u = s_keys[i];
            if ((u & hmask) == prefix) atomicAdd(&hist[(u >> shift) & 0xFF], 1);
        }
        __syncthreads();
        sufs[tid] = hist[tid];
        __syncthreads();
#pragma unroll
        for (int off = 1; off < 256; off <<= 1) {
            int add = (tid + off < 256) ? sufs[tid + off] : 0;
            __syncthreads();
            sufs[tid] += add;
            __syncthreads();
        }
        if (sufs[tid] >= krem && (tid == 255 || sufs[tid + 1] < krem)) {
            s_misc[0] = tid;
            s_misc[1] = sufs[tid] - hist[tid];
        }
        __syncthreads();
        prefix |= ((unsigned)s_misc[0]) << shift;
        krem -= s_misc[1];
        __syncthreads();
    }
    unsigned v = prefix;
    if (tid == 0) s_misc[2] = 0;
    __syncthreads();
    int* out = top_idx + (size_t)row * KSEL;
    for (int i = tid; i < DF; i += 256) {
        if (s_keys[i] > v) {
            int p = atomicAdd(&s_misc[2], 1);
            out[p] = i;
        }
    }
    __syncthreads();
    int base = s_misc[2];
    int lane = tid & 63, wave = tid >> 6;
    int taken = 0;
    for (int chunk = 0; chunk < DF / 256; chunk++) {
        int i = chunk * 256 + tid;
        int flag = (s_keys[i] == v) ? 1 : 0;
        unsigned long long mb = __ballot(flag);
        int before = __popcll(mb & ((1ULL << lane) - 1ULL));
        if (lane == 0) s_wsums[wave] = __popcll(mb);
        __syncthreads();
        int woff = 0;
#pragma unroll
        for (int w = 0; w < 4; w++) if (w < wave) woff += s_wsums[w];
        int total = s_wsums[0] + s_wsums[1] + s_wsums[2] + s_wsums[3];
        int excl = woff + before;
        if (flag && (taken + excl) < krem) out[base + taken + excl] = i;
        taken += total;
        __syncthreads();
    }
}

// ---------------- DeepSets manifold: one block per token, one k per thread --------
__global__ __launch_bounds__(256) void manifold_kernel(
    const float* __restrict__ z, const int* __restrict__ top_idx,
    const float* __restrict__ phi1_w, const float* __restrict__ phi1_b,
    const float* __restrict__ ln1w, const float* __restrict__ ln1b,
    const float* __restrict__ phi2_w, const float* __restrict__ phi2_b,
    const float* __restrict__ ln2w, const float* __restrict__ ln2b,
    const float* __restrict__ rho1_w, const float* __restrict__ rho1_b,
    const float* __restrict__ rho2_w, const float* __restrict__ rho2_b,
    float* __restrict__ man) {
    __shared__ float s_ctxp[4 * DH];
    __shared__ float s_ctx[DH];

    int tid = threadIdx.x;
    int t = blockIdx.x;
    int lane = tid & 63, wave = tid >> 6;

    int idx = top_idx[(size_t)t * KSEL + tid];
    float a = gelu_fast(z[(size_t)t * DF + idx]);
    f32x2 a2 = {a, a};

    f32x2 gv[DH2 / 2];
    f32x2 sv = {0.f, 0.f}, qv = {0.f, 0.f};
#pragma unroll
    for (int i = 0; i < DH2 / 2; i++) {
        f32x2 w = ((const f32x2*)phi1_w)[i];
        f32x2 b = ((const f32x2*)phi1_b)[i];
        f32x2 e = pkfma(a2, w, b);
        gv[i] = e;
        sv = sv + e;
        qv = pkfma(e, e, qv);
    }
    float s = sv.x + sv.y, s2 = qv.x + qv.y;
    float mu = s * (1.0f / DH2);
    float rs = rsqrtf(s2 * (1.0f / DH2) - mu * mu + 1e-5f);
    f32x2 muv = {mu, mu}, rsv = {rs, rs};
#pragma unroll
    for (int i = 0; i < DH2 / 2; i++) {
        f32x2 t2 = (gv[i] - muv) * rsv;
        t2 = pkfma(t2, ((const f32x2*)ln1w)[i], ((const f32x2*)ln1b)[i]);
        gv[i] = (f32x2){gelu_fast(t2.x), gelu_fast(t2.y)};
    }

    f32x2 hv[DH / 2];
#pragma unroll
    for (int j2 = 0; j2 < DH / 2; j2++) {
        const f32x2* wa = (const f32x2*)(phi2_w + (2 * j2) * DH2);
        const f32x2* wb = (const f32x2*)(phi2_w + (2 * j2 + 1) * DH2);
        f32x2 ra = {phi2_b[2 * j2], 0.f};
        f32x2 rb = {phi2_b[2 * j2 + 1], 0.f};
#pragma unroll
        for (int i = 0; i < DH2 / 2; i++) {
            ra = pkfma(gv[i], wa[i], ra);
            rb = pkfma(gv[i], wb[i], rb);
        }
        hv[j2] = (f32x2){ra.x + ra.y, rb.x + rb.y};
    }

    f32x2 tsv = {0.f, 0.f}, tqv = {0.f, 0.f};
#pragma unroll
    for (int j2 = 0; j2 < DH / 2; j2++) {
        tsv = tsv + hv[j2];
        tqv = pkfma(hv[j2], hv[j2], tqv);
    }
    float tsum = tsv.x + tsv.y, tsq = tqv.x + tqv.y;
    float mu2 = tsum * (1.0f / DH);
    float rs2 = rsqrtf(tsq * (1.0f / DH) - mu2 * mu2 + 1e-5f);
    f32x2 mu2v = {mu2, mu2}, rs2v = {rs2, rs2};
#pragma unroll
    for (int j2 = 0; j2 < DH / 2; j2++) {
        f32x2 t2 = (hv[j2] - mu2v) * rs2v;
        hv[j2] = pkfma(t2, ((const f32x2*)ln2w)[j2], ((const f32x2*)ln2b)[j2]);
    }

#pragma unroll
    for (int j2 = 0; j2 < DH / 2; j2++) {
        float vx = hv[j2].x, vy = hv[j2].y;
#pragma unroll
        for (int st = 1; st < 64; st <<= 1) {
            vx += __shfl_xor(vx, st);
            vy += __shfl_xor(vy, st);
        }
        if (lane == 0) {
            s_ctxp[wave * DH + 2 * j2] = vx;
            s_ctxp[wave * DH + 2 * j2 + 1] = vy;
        }
    }
    __syncthreads();
    if (tid < DH)
        s_ctx[tid] = (s_ctxp[tid] + s_ctxp[DH + tid] + s_ctxp[2 * DH + tid] +
                      s_ctxp[3 * DH + tid]) * (1.0f / KSEL);
    __syncthreads();

#pragma unroll
    for (int j2 = 0; j2 < DH / 2; j2++) hv[j2] = hv[j2] + ((const f32x2*)s_ctx)[j2];
    float m = rho2_b[0];
    for (int p = 0; p < 2 * DH; p++) {
        const f32x2* wp = (const f32x2*)(rho1_w + p * DH);
        f32x2 r0 = {rho1_b[p], 0.f};
        f32x2 r1 = {0.f, 0.f};
#pragma unroll
        for (int q2 = 0; q2 < DH / 2; q2 += 2) {
            r0 = pkfma(hv[q2], wp[q2], r0);
            r1 = pkfma(hv[q2 + 1], wp[q2 + 1], r1);
        }
        float r = (r0.x + r0.y) + (r1.x + r1.y);
        m = fmaf(gelu_fast(r), rho2_w[p], m);
    }
    man[(size_t)t * KSEL + tid] = m;
}

// ---------------- scatter man (as bf16) into zeroed bf16 a_man --------------------
__global__ __launch_bounds__(256) void scatter_bf16_kernel(const float* __restrict__ man,
                                                           const int* __restrict__ top_idx,
                                                           short* __restrict__ a_man) {
    int t = blockIdx.x, k = threadIdx.x;
    a_man[(size_t)t * DF + top_idx[(size_t)t * KSEL + k]] =
        (short)bf16_rne(man[(size_t)t * KSEL + k]);
}

extern "C" void kernel_launch(void* const* d_in, const int* in_sizes, int n_in,
                              void* d_out, int out_size, void* d_ws, size_t ws_size,
                              hipStream_t stream) {
    const float* x      = (const float*)d_in[0];
    const float* W1     = (const float*)d_in[1];
    const float* W2     = (const float*)d_in[2];
    const float* Wr1    = (const float*)d_in[3];
    const float* Wr2    = (const float*)d_in[4];
    const float* ln_w   = (const float*)d_in[5];
    const float* ln_b   = (const float*)d_in[6];
    const float* phi1_w = (const float*)d_in[7];
    const float* phi1_b = (const float*)d_in[8];
    const float* pl1w   = (const float*)d_in[9];
    const float* pl1b   = (const float*)d_in[10];
    const float* phi2_w = (const float*)d_in[11];
    const float* phi2_b = (const float*)d_in[12];
    const float* pl2w   = (const float*)d_in[13];
    const float* pl2b   = (const float*)d_in[14];
    const float* rho1_w = (const float*)d_in[15];
    const float* rho1_b = (const float*)d_in[16];
    const float* rho2_w = (const float*)d_in[17];
    const float* rho2_b = (const float*)d_in[18];
    float* out = (float*)d_out;

    char* ws = (char*)d_ws;
    size_t off = 0;
    auto alloc = [&](size_t bytes) {
        char* p = ws + off;
        off += (bytes + 255) & ~(size_t)255;
        return p;
    };
    float* xn     = (float*)alloc(sizeof(float) * (size_t)T_TOKENS * DM);   // 16 MB
    float* h      = (float*)alloc(sizeof(float) * (size_t)T_TOKENS * DM);   // 16 MB
    float* scores = (float*)alloc(sizeof(float) * (size_t)T_TOKENS * DF);   // 64 MB
    float* z      = (float*)alloc(sizeof(float) * (size_t)T_TOKENS * DF);   // 64 MB
    int*   tidx   = (int*)alloc(sizeof(int) * (size_t)T_TOKENS * KSEL);     // 4 MB
    float* man    = (float*)alloc(sizeof(float) * (size_t)T_TOKENS * KSEL); // 4 MB

    // Region reuse (stream-serial, lifetimes disjoint):
    short* xcat  = (short*)xn;      // [4096 x 2048] = 16 MB: [xh | xl], after GEMM1
    short* w1cat = (short*)h;       // [4096 x 2048] = 16 MB: [w1l | w1h], after GEMM2
    short* amanb = (short*)scores;  // 32 MB, after topk
    short* w2b   = (short*)z;       // 8 MB, after manifold

    // 1. x_norm = LN(x)
    ln_kernel<<<T_TOKENS, 256, 0, stream>>>(x, ln_w, ln_b, xn);
    // 2. h = gelu(xn @ Wr1^T)   (fp32 + libm erff — bitwise stable for top-k)
    gemm_f32_128<<<dim3(DM / 128, T_TOKENS / 128), 256, 0, stream>>>(xn, Wr1, h, T_TOKENS, DM, DM, 1);
    // 3. scores = h @ Wr2^T     (fp32)
    gemm_f32_128<<<dim3(DF / 128, T_TOKENS / 128), 256, 0, stream>>>(h, Wr2, scores, T_TOKENS, DF, DM, 0);
    // 4. top_idx
    topk_kernel<<<T_TOKENS, 256, 0, stream>>>(scores, tidx);
    // 5. split x -> [xh|xl], W1 -> [w1l|w1h]
    cvt_split_cat_kernel<<<(T_TOKENS * DM / 4 + 255) / 256, 256, 0, stream>>>(x, xcat, T_TOKENS * DM / 4, 0);
    cvt_split_cat_kernel<<<(DF * DM / 4 + 255) / 256, 256, 0, stream>>>(W1, w1cat, DF * DM / 4, 1);
    // 6. z = x @ W1^T: hi*hi (K=1024) + merged cross terms (K=2048)
    gemm_bf16<<<dim3(DF / 128, T_TOKENS / 128), 256, 0, stream>>>(
        xcat, w1cat + DM, z, T_TOKENS, DF, DM, 2 * DM, 2 * DM, 0);
    gemm_bf16<<<dim3(DF / 128, T_TOKENS / 128), 256, 0, stream>>>(
        xcat, w1cat, z, T_TOKENS, DF, 2 * DM, 2 * DM, 2 * DM, 1);
    // 7. manifold (pk-fma)
    manifold_kernel<<<T_TOKENS, 256, 0, stream>>>(z, tidx, phi1_w, phi1_b, pl1w, pl1b,
                                                  phi2_w, phi2_b, pl2w, pl2b,
                                                  rho1_w, rho1_b, rho2_w, rho2_b, man);
    // 8. scatter man -> bf16 a_man; W2 -> bf16
    hipMemsetAsync(amanb, 0, sizeof(short) * (size_t)T_TOKENS * DF, stream);
    scatter_bf16_kernel<<<T_TOKENS, 256, 0, stream>>>(man, tidx, amanb);
    cvt_bf16_kernel<<<(DM * DF / 4 + 255) / 256, 256, 0, stream>>>(W2, w2b, DM * DF / 4);
    // 9. out = a_man @ W2^T  (plain bf16 MFMA)
    gemm_bf16<<<dim3(DM / 128, T_TOKENS / 128), 256, 0, stream>>>(
        amanb, w2b, out, T_TOKENS, DM, DF, DF, DF, 0);
}